// Round 13
// baseline (54.667 us; speedup 1.0000x reference)
//
#include <hip/hip_runtime.h>

#define N_    32
#define CIN   128
#define H_    56
#define W_    56
#define HW_   (H_ * W_)
#define COUT  256
#define GROUPS 4
#define CPG   32      // in-channels per group
#define OPG   64      // out-channels per group
#define CDIM  64
#define HP    58      // padded spatial dim (1-px zero halo each side)

#define ROWB  (HP * CPG)      // bf16 per padded row = 1856 (3712 B)

#define TH    2               // output rows per (single-wave) block
#define NPIX  (TH * W_)       // 112
#define NT    (NPIX / 16)     // 7 pixel tiles per wave
#define SCHUNKS 15            // ceil(4*3712/1024) 1KB staging chunks
#define LDS_B (SCHUNKS * 1024)

// fallback-path tile geometry (R2 kernel)
#define FB_TH   8
#define HALO_R (FB_TH + 2)
#define HALO_C (W_ + 2)
#define XPLANE (HALO_R * HALO_C)

typedef __bf16 bf16x8 __attribute__((ext_vector_type(8)));
typedef __bf16 bf16x2 __attribute__((ext_vector_type(2)));
typedef float  f32x4  __attribute__((ext_vector_type(4)));
typedef unsigned int u32x4 __attribute__((ext_vector_type(4)));

__device__ __forceinline__ void gload16(const void* g, void* l) {
    __builtin_amdgcn_global_load_lds((const __attribute__((address_space(1))) void*)g,
                                     (__attribute__((address_space(3))) void*)l, 16, 0, 0);
}

// ---------- merged pre-kernel: xpose (7424) + ctx (32) + wconv (36) ----------
// xt layout: [n][g][58 rows][58 pixels][4 slots][8 ic] bf16; octet o of pixel pix
// stored at slot o ^ ((pix>>1)&3)  (LDS bank swizzle; read applies the same XOR).
__global__ __launch_bounds__(256) void pre_kernel(
    const float* __restrict__ x, const float* __restrict__ c,
    const float* __restrict__ wgt, const float* __restrict__ bias,
    const float* __restrict__ cw,
    __bf16* __restrict__ xt, float* __restrict__ gctx, __bf16* __restrict__ wbf)
{
    const int bid = blockIdx.x;
    const int tid = threadIdx.x;

    if (bid < HP * GROUPS * N_) {                 // ---- xpose ----
        const int hh = bid % HP;
        const int g  = (bid / HP) & (GROUPS - 1);
        const int n  = bid / (HP * GROUPS);
        uint* drow = (uint*)(xt + ((size_t)(n * GROUPS + g) * HP + hh) * ROWB);  // 928 dwords
        const int h = hh - 1;
        if ((unsigned)h >= (unsigned)H_) {        // top/bottom halo row: zeros
            for (int j = tid; j < HP * CPG / 2; j += 256) drow[j] = 0u;
            return;
        }
        __shared__ float t[W_][33];               // [w][ic], pad 33 -> conflict-free
        const float* src = x + ((size_t)(n * CIN + g * CPG) * H_ + h) * W_;
        for (int j = tid; j < CPG * W_; j += 256) {   // coalesced along w
            int ic = j / W_, w = j - ic * W_;
            t[w][ic] = src[(size_t)ic * HW_ + w];
        }
        __syncthreads();
        for (int j = tid; j < HP * CPG / 2; j += 256) {   // 928 dwords, coalesced
            int pix = j >> 4, icp = j & 15;
            int w = pix - 1;
            uint val = 0u;
            if ((unsigned)w < (unsigned)W_) {
                bf16x2 v;
                v[0] = (__bf16)t[w][icp * 2];
                v[1] = (__bf16)t[w][icp * 2 + 1];
                val = __builtin_bit_cast(unsigned int, v);
            }
            int o = icp >> 2, d = icp & 3;
            int slot = o ^ ((pix >> 1) & 3);
            drow[(pix << 4) + (slot << 2) + d] = val;
        }
    } else if (bid < HP * GROUPS * N_ + N_) {     // ---- ctx ----
        const int n  = bid - HP * GROUPS * N_;
        const int oc = tid;
        const float* cn  = c  + n * CDIM;
        const float* cwo = cw + oc * CDIM;
        float s = bias[oc];
        #pragma unroll
        for (int d = 0; d < CDIM; ++d) s += cn[d] * cwo[d];
        gctx[n * COUT + oc] = s;
    } else {                                      // ---- wconv: bf16 [g][tap][oct][ocL][8] ----
        int j = (bid - (HP * GROUPS * N_ + N_)) * 256 + tid;
        int e   = j & 7;
        int r   = j >> 3;
        int ocL = r & 63;  r >>= 6;
        int o   = r & 3;   r >>= 2;               // ic octet
        int tap = r % 9;
        int g   = r / 9;
        int ic  = o * 8 + e;
        wbf[j] = (__bf16)wgt[((g * OPG + ocL) * CPG + ic) * 9 + tap];
    }
}

// ---------- main kernel: BARRIER-FREE single-wave blocks ----------
// Block = 1 wave (64 thr). Each wave stages its own 4 padded xt rows (14.8KB LDS,
// 15 gload_lds) and computes 2 output rows x all 4 oc-tiles. NO __syncthreads:
// one per-wave s_waitcnt vmcnt(0) + sched_barrier replaces the block-wide barrier,
// so co-resident waves free-run (one wave's staging overlaps another's MFMA with
// no phase coupling). a[4][9] pins live in the unified VGPR/AGPR file (MFMA
// sources AGPRs directly). Operand-swapped MFMA keeps dwordx4 stores.
__global__ __attribute__((amdgpu_flat_work_group_size(64, 64)))
void conv_main(
    const __bf16* __restrict__ xt, const __bf16* __restrict__ wbf,
    const float* __restrict__ gctx, float* __restrict__ out)
{
    __shared__ __align__(16) __bf16 x_lds[LDS_B / 2];   // 15360 B

    const int ht  = blockIdx.x;   // 0..27 (2-row strip)
    const int g   = blockIdx.y;   // 0..3
    const int n   = blockIdx.z;   // 0..31
    const int lane = threadIdx.x; // 0..63
    const int h0  = ht * TH;      // first output row; padded rows h0..h0+3

    const int l15  = lane & 15;      // oc within tile / b-frag pixel row
    const int kh4  = lane >> 4;      // k octet; D pixel-quad group

    // ---- stage this wave's 4 padded rows (15 x 1KB chunks; 512B tail slack
    //      stays inside xt/d_ws and is never read back) ----
    {
        const char* sbase = (const char*)(xt + ((size_t)(n * GROUPS + g) * HP + h0) * ROWB);
        char* lbase = (char*)&x_lds[0];
        #pragma unroll
        for (int ch = 0; ch < SCHUNKS; ++ch)
            gload16(sbase + ch * 1024 + lane * 16, lbase + ch * 1024);
    }

    // ---- w-frags (all 4 oc-tiles) from pre-permuted global; pin (VGPR/AGPR) ----
    u32x4 a[4][9];
    {
        const __bf16* wgb = wbf + (size_t)g * (9 * 4 * OPG * 8);
        #pragma unroll
        for (int i = 0; i < 4; ++i)
            #pragma unroll
            for (int tap = 0; tap < 9; ++tap)
                a[i][tap] = *(const u32x4*)&wgb[(((tap * 4 + kh4) * OPG) + i * 16 + l15) * 8];
    }
    #pragma unroll
    for (int i = 0; i < 4; ++i)
        #pragma unroll
        for (int tap = 0; tap < 9; ++tap)
            asm volatile("" : "+v"(a[i][tap]));

    float ctxv[4];
    #pragma unroll
    for (int i = 0; i < 4; ++i)
        ctxv[i] = gctx[n * COUT + g * OPG + i * 16 + l15];

    // per-wave drain of all VMEM (staging + a-frags + ctx); rule-#18 fence keeps
    // the compiler from hoisting LDS reads / MFMA above it
    asm volatile("s_waitcnt vmcnt(0)" ::: "memory");
    __builtin_amdgcn_sched_barrier(0);

    // lane's output rows: oc = g*OPG + i*16 + l15
    float* outb0 = out + ((size_t)n * COUT + g * OPG + l15) * HW_ + h0 * W_;

    #pragma unroll 1
    for (int t = 0; t < NT; ++t) {
        int p  = t * 16 + l15;           // b-frag pixel (A-operand row), 0..111
        int pr = p / W_;                 // 0..1
        int pc = p - pr * W_;
        f32x4 acc0 = {ctxv[0], ctxv[0], ctxv[0], ctxv[0]};
        f32x4 acc1 = {ctxv[1], ctxv[1], ctxv[1], ctxv[1]};
        f32x4 acc2 = {ctxv[2], ctxv[2], ctxv[2], ctxv[2]};
        f32x4 acc3 = {ctxv[3], ctxv[3], ctxv[3], ctxv[3]};
        #pragma unroll
        for (int kh = 0; kh < 3; ++kh) {
            #pragma unroll
            for (int kw = 0; kw < 3; ++kw) {
                int pix = pc + kw;
                int idx = (pr + kh) * ROWB + pix * CPG + ((kh4 ^ ((pix >> 1) & 3)) << 3);
                const bf16x8 b = *(const bf16x8*)&x_lds[idx];
                const int tp = kh * 3 + kw;
                acc0 = __builtin_amdgcn_mfma_f32_16x16x32_bf16(
                           b, __builtin_bit_cast(bf16x8, a[0][tp]), acc0, 0, 0, 0);
                acc1 = __builtin_amdgcn_mfma_f32_16x16x32_bf16(
                           b, __builtin_bit_cast(bf16x8, a[1][tp]), acc1, 0, 0, 0);
                acc2 = __builtin_amdgcn_mfma_f32_16x16x32_bf16(
                           b, __builtin_bit_cast(bf16x8, a[2][tp]), acc2, 0, 0, 0);
                acc3 = __builtin_amdgcn_mfma_f32_16x16x32_bf16(
                           b, __builtin_bit_cast(bf16x8, a[3][tp]), acc3, 0, 0, 0);
            }
        }
        // lane stores 4 consecutive pixels per oc-tile (16B aligned; 56%4==0 and
        // the 2-row strip is 112 contiguous floats per oc row, so no straddle)
        int p0 = t * 16 + kh4 * 4;
        *(f32x4*)&outb0[p0]                      = acc0;
        *(f32x4*)&outb0[p0 + (size_t)16 * HW_]   = acc1;
        *(f32x4*)&outb0[p0 + (size_t)32 * HW_]   = acc2;
        *(f32x4*)&outb0[p0 + (size_t)48 * HW_]   = acc3;
    }
}

// ---------- fallback (R2 structure) if workspace can't hold xt ----------
__global__ void ctx_kernel_fb(const float* __restrict__ c, const float* __restrict__ bias,
                              const float* __restrict__ cw, float* __restrict__ gctx) {
    const int n  = blockIdx.x;
    const int oc = threadIdx.x;
    const float* cn  = c  + n * CDIM;
    const float* cwo = cw + oc * CDIM;
    float s = bias[oc];
    #pragma unroll
    for (int d = 0; d < CDIM; ++d) s += cn[d] * cwo[d];
    gctx[n * COUT + oc] = s;
}
__global__ void wconv_kernel_fb(const float* __restrict__ wgt, __bf16* __restrict__ wbf) {
    int j = blockIdx.x * 256 + threadIdx.x;
    int e   = j & 7;
    int r   = j >> 3;
    int ocL = r & 63;  r >>= 6;
    int o   = r & 3;   r >>= 2;
    int tap = r % 9;
    int g   = r / 9;
    int ic  = o * 8 + e;
    wbf[j] = (__bf16)wgt[((g * OPG + ocL) * CPG + ic) * 9 + tap];
}
__global__ __launch_bounds__(512, 4) void ctx_conv_fb(
    const float* __restrict__ x, const __bf16* __restrict__ wbf,
    const float* __restrict__ gctx, float* __restrict__ out)
{
    __shared__ __align__(16) __bf16 x_lds[XPLANE][CPG];
    const int ht  = blockIdx.x;
    const int g   = blockIdx.y;
    const int n   = blockIdx.z;
    const int tid = threadIdx.x;
    const int h0  = ht * FB_TH;
    const int wv   = tid >> 6;
    const int lane = tid & 63;
    const int l15  = lane & 15;
    const int kh4  = lane >> 4;
    const int p2   = (wv & 1) * 2;
    const int pq   = wv >> 1;

    bf16x8 a[2][9];
    {
        const __bf16* wgb = wbf + (size_t)g * (9 * 4 * OPG * 8);
        #pragma unroll
        for (int i = 0; i < 2; ++i)
            #pragma unroll
            for (int tap = 0; tap < 9; ++tap)
                a[i][tap] = *(const bf16x8*)&wgb[(((tap * 4 + kh4) * OPG) + (p2 + i) * 16 + l15) * 8];
    }
    float ctxv[2][4];
    #pragma unroll
    for (int i = 0; i < 2; ++i)
        #pragma unroll
        for (int r = 0; r < 4; ++r)
            ctxv[i][r] = gctx[n * COUT + g * OPG + (p2 + i) * 16 + kh4 * 4 + r];
    {
        const float* xg = x + ((size_t)n * CIN + g * CPG) * HW_;
        for (int j = tid; j < 4 * XPLANE; j += 512) {
            int pix = j >> 2;
            int oct = j & 3;
            int hr = pix / HALO_C;
            int wc = pix - hr * HALO_C;
            int hg  = h0 - 1 + hr;
            int wg2 = wc - 1;
            bool valid = ((unsigned)hg < (unsigned)H_) && ((unsigned)wg2 < (unsigned)W_);
            const float* src = xg + (size_t)(oct * 8) * HW_ + hg * W_ + wg2;
            bf16x8 v;
            #pragma unroll
            for (int e = 0; e < 8; ++e)
                v[e] = (__bf16)(valid ? src[(size_t)e * HW_] : 0.f);
            *(bf16x8*)&x_lds[pix][oct * 8] = v;
        }
    }
    __syncthreads();
    float* outb = out + ((size_t)n * COUT + g * OPG + p2 * 16 + kh4 * 4) * HW_ + h0 * W_;
    #pragma unroll 1
    for (int t = pq * 7; t < pq * 7 + 7; ++t) {
        int p  = t * 16 + l15;
        int pr = p / W_;
        int pc = p - pr * W_;
        f32x4 acc0 = {0.f, 0.f, 0.f, 0.f};
        f32x4 acc1 = {0.f, 0.f, 0.f, 0.f};
        #pragma unroll
        for (int kh = 0; kh < 3; ++kh) {
            #pragma unroll
            for (int kw = 0; kw < 3; ++kw) {
                const bf16x8 b = *(const bf16x8*)&x_lds[(pr + kh) * HALO_C + (pc + kw)][kh4 * 8];
                acc0 = __builtin_amdgcn_mfma_f32_16x16x32_bf16(a[0][kh * 3 + kw], b, acc0, 0, 0, 0);
                acc1 = __builtin_amdgcn_mfma_f32_16x16x32_bf16(a[1][kh * 3 + kw], b, acc1, 0, 0, 0);
            }
        }
        #pragma unroll
        for (int r = 0; r < 4; ++r)
            outb[(size_t)r * HW_ + p] = acc0[r] + ctxv[0][r];
        #pragma unroll
        for (int r = 0; r < 4; ++r)
            outb[(size_t)(16 + r) * HW_ + p] = acc1[r] + ctxv[1][r];
    }
}

extern "C" void kernel_launch(void* const* d_in, const int* in_sizes, int n_in,
                              void* d_out, int out_size, void* d_ws, size_t ws_size,
                              hipStream_t stream) {
    const float* x    = (const float*)d_in[0];
    const float* c    = (const float*)d_in[1];
    const float* wgt  = (const float*)d_in[2];
    const float* bias = (const float*)d_in[3];
    const float* cw   = (const float*)d_in[4];
    float* out = (float*)d_out;

    const size_t XT_BYTES   = (size_t)N_ * GROUPS * HP * HP * CPG * 2;   // 27,557,888
    const size_t GCTX_BYTES = (size_t)N_ * COUT * 4;                     // 32,768
    const size_t WBF_BYTES  = (size_t)COUT * CPG * 9 * 2;                // 147,456
    const size_t NEEDED     = XT_BYTES + GCTX_BYTES + WBF_BYTES;

    if (ws_size >= NEEDED) {
        __bf16* xt   = (__bf16*)d_ws;
        float*  gctx = (float*)((char*)d_ws + XT_BYTES);
        __bf16* wbf  = (__bf16*)((char*)d_ws + XT_BYTES + GCTX_BYTES);

        const int nxpose = HP * GROUPS * N_;                       // 7424
        const int npre   = nxpose + N_ + (COUT * CPG * 9) / 256;   // +32 +36
        pre_kernel<<<dim3(npre), 256, 0, stream>>>(x, c, wgt, bias, cw, xt, gctx, wbf);

        dim3 grid(H_ / TH, GROUPS, N_);   // (28, 4, 32) = 3584 blocks x 64 thr
        conv_main<<<grid, 64, 0, stream>>>(xt, wbf, gctx, out);
    } else {
        float*  gctx = (float*)d_ws;
        __bf16* wbf  = (__bf16*)((char*)d_ws + 32768);
        ctx_kernel_fb<<<dim3(N_), 256, 0, stream>>>(c, bias, cw, gctx);
        wconv_kernel_fb<<<dim3((COUT * CPG * 9) / 256), 256, 0, stream>>>(wgt, wbf);
        dim3 grid(H_ / FB_TH, GROUPS, N_);
        ctx_conv_fb<<<grid, 512, 0, stream>>>(x, wbf, gctx, out);
    }
}

// Round 14
// 47.311 us; speedup vs baseline: 1.1555x; 1.1555x over previous
//
#include <hip/hip_runtime.h>

#define N_    32
#define CIN   128
#define H_    56
#define W_    56
#define HW_   (H_ * W_)
#define COUT  256
#define GROUPS 4
#define CPG   32      // in-channels per group
#define OPG   64      // out-channels per group
#define CDIM  64
#define HP    58      // padded spatial dim (1-px zero halo each side)

#define TH    8               // output rows per block
#define NPIX  (TH * W_)       // 448
#define NT    (NPIX / 16)     // 28 pixel tiles (14 per wave-half)

#define ROWB  (HP * CPG)      // bf16 per padded row = 1856 (3712 B)
#define STRIP_CHUNKS 37       // ceil(10*3712 / 1024)

// fallback-path tile geometry (R2 kernel)
#define FB_TH   8
#define HALO_R (FB_TH + 2)
#define HALO_C (W_ + 2)
#define XPLANE (HALO_R * HALO_C)

typedef __bf16 bf16x8 __attribute__((ext_vector_type(8)));
typedef __bf16 bf16x2 __attribute__((ext_vector_type(2)));
typedef float  f32x4  __attribute__((ext_vector_type(4)));
typedef unsigned int u32x4 __attribute__((ext_vector_type(4)));

__device__ __forceinline__ void gload16(const void* g, void* l) {
    __builtin_amdgcn_global_load_lds((const __attribute__((address_space(1))) void*)g,
                                     (__attribute__((address_space(3))) void*)l, 16, 0, 0);
}

__device__ __forceinline__ uint packbf2(float a, float b) {
    bf16x2 v; v[0] = (__bf16)a; v[1] = (__bf16)b;
    return __builtin_bit_cast(unsigned int, v);
}

// ---------- merged pre-kernel: xpose (7424) + ctx (32) + wconv (36) ----------
// xt layout: [n][g][58 rows][58 pixels][4 slots][8 ic] bf16; octet o of pixel pix
// stored at slot o ^ ((pix>>1)&3)  (LDS bank swizzle; main's read applies same XOR).
// VECTORIZED: float4 global reads (448/row vs 1792 scalar), dwordx4 global writes
// (232/row vs 928 scalar) — pre was VMEM-issue-bound, not BW-bound.
__global__ __launch_bounds__(256) void pre_kernel(
    const float* __restrict__ x, const float* __restrict__ c,
    const float* __restrict__ wgt, const float* __restrict__ bias,
    const float* __restrict__ cw,
    __bf16* __restrict__ xt, float* __restrict__ gctx, __bf16* __restrict__ wbf)
{
    const int bid = blockIdx.x;
    const int tid = threadIdx.x;

    if (bid < HP * GROUPS * N_) {                 // ---- xpose (one padded row) ----
        const int hh = bid % HP;
        const int g  = (bid / HP) & (GROUPS - 1);
        const int n  = bid / (HP * GROUPS);
        u32x4* drow4 = (u32x4*)(xt + ((size_t)(n * GROUPS + g) * HP + hh) * ROWB);  // 232 dwordx4
        const int h = hh - 1;
        if ((unsigned)h >= (unsigned)H_) {        // top/bottom halo row: zeros
            if (tid < 232) drow4[tid] = (u32x4){0u, 0u, 0u, 0u};
            return;
        }
        __shared__ float t[CPG][57];              // [ic][w]; pad 57 -> e-gather ~2-way
        const float* src = x + ((size_t)(n * CIN + g * CPG) * H_ + h) * W_;
        // load: 448 float4 jobs (ic 0..31, q 0..13), coalesced 224B runs per ic
        for (int j = tid; j < CPG * (W_ / 4); j += 256) {
            int ic = j / 14, q = j - ic * 14;
            f32x4 v = *(const f32x4*)&src[(size_t)ic * HW_ + q * 4];
            #pragma unroll
            for (int k = 0; k < 4; ++k) t[ic][q * 4 + k] = v[k];
        }
        __syncthreads();
        // store: 232 dwordx4 jobs; j -> pix=j>>2, slot=j&3, oct = slot ^ ((pix>>1)&3)
        if (tid < HP * 4) {
            int pix = tid >> 2;
            int oct = (tid & 3) ^ ((pix >> 1) & 3);
            int w = pix - 1;
            u32x4 o4 = {0u, 0u, 0u, 0u};
            if ((unsigned)w < (unsigned)W_) {
                #pragma unroll
                for (int dd = 0; dd < 4; ++dd)
                    o4[dd] = packbf2(t[oct * 8 + dd * 2][w], t[oct * 8 + dd * 2 + 1][w]);
            }
            drow4[tid] = o4;
        }
    } else if (bid < HP * GROUPS * N_ + N_) {     // ---- ctx ----
        const int n  = bid - HP * GROUPS * N_;
        const int oc = tid;
        const float* cn  = c  + n * CDIM;
        const float* cwo = cw + oc * CDIM;
        float s = bias[oc];
        #pragma unroll
        for (int d = 0; d < CDIM; ++d) s += cn[d] * cwo[d];
        gctx[n * COUT + oc] = s;
    } else {                                      // ---- wconv: bf16 [g][tap][oct][ocL][8] ----
        int j = (bid - (HP * GROUPS * N_ + N_)) * 256 + tid;
        int e   = j & 7;
        int r   = j >> 3;
        int ocL = r & 63;  r >>= 6;
        int o   = r & 3;   r >>= 2;               // ic octet
        int tap = r % 9;
        int g   = r / 9;
        int ic  = o * 8 + e;
        wbf[j] = (__bf16)wgt[((g * OPG + ocL) * CPG + ic) * 9 + tap];
    }
}

// ---------- main kernel: R10 verbatim (best measured, 49.9) ----------
__global__ __launch_bounds__(256, 4) void conv_main(
    const __bf16* __restrict__ xt, const __bf16* __restrict__ wbf,
    const float* __restrict__ gctx, float* __restrict__ out)
{
    __shared__ __align__(16) __bf16 x_lds[(STRIP_CHUNKS * 1024) / 2];   // 37888 B

    const int ht  = blockIdx.x;   // 0..6  (8-row strip)
    const int g   = blockIdx.y;   // 0..3
    const int n   = blockIdx.z;   // 0..31
    const int tid = threadIdx.x;  // 0..255 (4 waves)
    const int h0  = ht * TH;

    const int wv   = tid >> 6;       // 0..3
    const int lane = tid & 63;
    const int l15  = lane & 15;
    const int kh4  = lane >> 4;      // ic octet / D pixel-quad group
    const int p2   = (wv & 1) * 2;   // oc-tile pair base (0 or 2)
    const int ph   = wv >> 1;        // pixel half (14 tiles each)

    // ---- stage strip rows h0..h0+9 FIRST (latency overlaps loads below) ----
    {
        const char* sbase = (const char*)(xt + ((size_t)(n * GROUPS + g) * HP + h0) * ROWB);
        char* lbase = (char*)&x_lds[0];
        for (int ch = wv; ch < STRIP_CHUNKS; ch += 4)     // wave-uniform dest base
            gload16(sbase + ch * 1024 + lane * 16, lbase + ch * 1024);
        // (chunk 36 copies 768B of tail slack; stays inside d_ws, never read)
    }

    // ---- w-frags from pre-permuted global; PIN so compiler can't sink ----
    u32x4 a[2][9];
    {
        const __bf16* wgb = wbf + (size_t)g * (9 * 4 * OPG * 8);
        #pragma unroll
        for (int i = 0; i < 2; ++i)
            #pragma unroll
            for (int tap = 0; tap < 9; ++tap)
                a[i][tap] = *(const u32x4*)&wgb[(((tap * 4 + kh4) * OPG) + (p2 + i) * 16 + l15) * 8];
    }
    #pragma unroll
    for (int i = 0; i < 2; ++i)
        #pragma unroll
        for (int tap = 0; tap < 9; ++tap)
            asm volatile("" : "+v"(a[i][tap]));

    // ctx for this lane's oc (one per oc-tile) — coalesced 64B loads
    float ctxv[2];
    #pragma unroll
    for (int i = 0; i < 2; ++i)
        ctxv[i] = gctx[n * COUT + g * OPG + (p2 + i) * 16 + l15];

    __syncthreads();

    // lane's output rows: oc = g*OPG + (p2+i)*16 + l15
    float* outb0 = out + ((size_t)n * COUT + g * OPG + p2 * 16 + l15) * HW_ + h0 * W_;
    float* outb1 = outb0 + (size_t)16 * HW_;

    #pragma unroll 1
    for (int t = ph * 14; t < ph * 14 + 14; ++t) {
        int p  = t * 16 + l15;           // A-row pixel for LDS read
        int pr = p / W_;
        int pc = p - pr * W_;
        f32x4 acc0 = {ctxv[0], ctxv[0], ctxv[0], ctxv[0]};   // ctx as C-init
        f32x4 acc1 = {ctxv[1], ctxv[1], ctxv[1], ctxv[1]};
        #pragma unroll
        for (int kh = 0; kh < 3; ++kh) {
            #pragma unroll
            for (int kw = 0; kw < 3; ++kw) {
                int pix = pc + kw;
                int idx = (pr + kh) * ROWB + pix * CPG + ((kh4 ^ ((pix >> 1) & 3)) << 3);
                const bf16x8 b = *(const bf16x8*)&x_lds[idx];
                // swapped operands: D[m=pixel][n=oc]
                acc0 = __builtin_amdgcn_mfma_f32_16x16x32_bf16(
                           b, __builtin_bit_cast(bf16x8, a[0][kh * 3 + kw]), acc0, 0, 0, 0);
                acc1 = __builtin_amdgcn_mfma_f32_16x16x32_bf16(
                           b, __builtin_bit_cast(bf16x8, a[1][kh * 3 + kw]), acc1, 0, 0, 0);
            }
        }
        // lane writes 4 consecutive pixels for its oc in each oc-tile
        int p0 = t * 16 + kh4 * 4;
        *(f32x4*)&outb0[p0] = acc0;
        *(f32x4*)&outb1[p0] = acc1;
    }
}

// ---------- fallback (R2 structure) if workspace can't hold xt ----------
__global__ void ctx_kernel_fb(const float* __restrict__ c, const float* __restrict__ bias,
                              const float* __restrict__ cw, float* __restrict__ gctx) {
    const int n  = blockIdx.x;
    const int oc = threadIdx.x;
    const float* cn  = c  + n * CDIM;
    const float* cwo = cw + oc * CDIM;
    float s = bias[oc];
    #pragma unroll
    for (int d = 0; d < CDIM; ++d) s += cn[d] * cwo[d];
    gctx[n * COUT + oc] = s;
}
__global__ void wconv_kernel_fb(const float* __restrict__ wgt, __bf16* __restrict__ wbf) {
    int j = blockIdx.x * 256 + threadIdx.x;
    int e   = j & 7;
    int r   = j >> 3;
    int ocL = r & 63;  r >>= 6;
    int o   = r & 3;   r >>= 2;
    int tap = r % 9;
    int g   = r / 9;
    int ic  = o * 8 + e;
    wbf[j] = (__bf16)wgt[((g * OPG + ocL) * CPG + ic) * 9 + tap];
}
__global__ __launch_bounds__(512, 4) void ctx_conv_fb(
    const float* __restrict__ x, const __bf16* __restrict__ wbf,
    const float* __restrict__ gctx, float* __restrict__ out)
{
    __shared__ __align__(16) __bf16 x_lds[XPLANE][CPG];
    const int ht  = blockIdx.x;
    const int g   = blockIdx.y;
    const int n   = blockIdx.z;
    const int tid = threadIdx.x;
    const int h0  = ht * FB_TH;
    const int wv   = tid >> 6;
    const int lane = tid & 63;
    const int l15  = lane & 15;
    const int kh4  = lane >> 4;
    const int p2   = (wv & 1) * 2;
    const int pq   = wv >> 1;

    bf16x8 a[2][9];
    {
        const __bf16* wgb = wbf + (size_t)g * (9 * 4 * OPG * 8);
        #pragma unroll
        for (int i = 0; i < 2; ++i)
            #pragma unroll
            for (int tap = 0; tap < 9; ++tap)
                a[i][tap] = *(const bf16x8*)&wgb[(((tap * 4 + kh4) * OPG) + (p2 + i) * 16 + l15) * 8];
    }
    float ctxv[2][4];
    #pragma unroll
    for (int i = 0; i < 2; ++i)
        #pragma unroll
        for (int r = 0; r < 4; ++r)
            ctxv[i][r] = gctx[n * COUT + g * OPG + (p2 + i) * 16 + kh4 * 4 + r];
    {
        const float* xg = x + ((size_t)n * CIN + g * CPG) * HW_;
        for (int j = tid; j < 4 * XPLANE; j += 512) {
            int pix = j >> 2;
            int oct = j & 3;
            int hr = pix / HALO_C;
            int wc = pix - hr * HALO_C;
            int hg  = h0 - 1 + hr;
            int wg2 = wc - 1;
            bool valid = ((unsigned)hg < (unsigned)H_) && ((unsigned)wg2 < (unsigned)W_);
            const float* src = xg + (size_t)(oct * 8) * HW_ + hg * W_ + wg2;
            bf16x8 v;
            #pragma unroll
            for (int e = 0; e < 8; ++e)
                v[e] = (__bf16)(valid ? src[(size_t)e * HW_] : 0.f);
            *(bf16x8*)&x_lds[pix][oct * 8] = v;
        }
    }
    __syncthreads();
    float* outb = out + ((size_t)n * COUT + g * OPG + p2 * 16 + kh4 * 4) * HW_ + h0 * W_;
    #pragma unroll 1
    for (int t = pq * 7; t < pq * 7 + 7; ++t) {
        int p  = t * 16 + l15;
        int pr = p / W_;
        int pc = p - pr * W_;
        f32x4 acc0 = {0.f, 0.f, 0.f, 0.f};
        f32x4 acc1 = {0.f, 0.f, 0.f, 0.f};
        #pragma unroll
        for (int kh = 0; kh < 3; ++kh) {
            #pragma unroll
            for (int kw = 0; kw < 3; ++kw) {
                const bf16x8 b = *(const bf16x8*)&x_lds[(pr + kh) * HALO_C + (pc + kw)][kh4 * 8];
                acc0 = __builtin_amdgcn_mfma_f32_16x16x32_bf16(a[0][kh * 3 + kw], b, acc0, 0, 0, 0);
                acc1 = __builtin_amdgcn_mfma_f32_16x16x32_bf16(a[1][kh * 3 + kw], b, acc1, 0, 0, 0);
            }
        }
        #pragma unroll
        for (int r = 0; r < 4; ++r)
            outb[(size_t)r * HW_ + p] = acc0[r] + ctxv[0][r];
        #pragma unroll
        for (int r = 0; r < 4; ++r)
            outb[(size_t)(16 + r) * HW_ + p] = acc1[r] + ctxv[1][r];
    }
}

extern "C" void kernel_launch(void* const* d_in, const int* in_sizes, int n_in,
                              void* d_out, int out_size, void* d_ws, size_t ws_size,
                              hipStream_t stream) {
    const float* x    = (const float*)d_in[0];
    const float* c    = (const float*)d_in[1];
    const float* wgt  = (const float*)d_in[2];
    const float* bias = (const float*)d_in[3];
    const float* cw   = (const float*)d_in[4];
    float* out = (float*)d_out;

    const size_t XT_BYTES   = (size_t)N_ * GROUPS * HP * HP * CPG * 2;   // 27,557,888
    const size_t GCTX_BYTES = (size_t)N_ * COUT * 4;                     // 32,768
    const size_t WBF_BYTES  = (size_t)COUT * CPG * 9 * 2;                // 147,456
    const size_t NEEDED     = XT_BYTES + GCTX_BYTES + WBF_BYTES;

    if (ws_size >= NEEDED) {
        __bf16* xt   = (__bf16*)d_ws;
        float*  gctx = (float*)((char*)d_ws + XT_BYTES);
        __bf16* wbf  = (__bf16*)((char*)d_ws + XT_BYTES + GCTX_BYTES);

        const int nxpose = HP * GROUPS * N_;                       // 7424
        const int npre   = nxpose + N_ + (COUT * CPG * 9) / 256;   // +32 +36
        pre_kernel<<<dim3(npre), 256, 0, stream>>>(x, c, wgt, bias, cw, xt, gctx, wbf);

        dim3 grid(H_ / TH, GROUPS, N_);   // (7, 4, 32) = 896 blocks x 256 thr
        conv_main<<<grid, 256, 0, stream>>>(xt, wbf, gctx, out);
    } else {
        float*  gctx = (float*)d_ws;
        __bf16* wbf  = (__bf16*)((char*)d_ws + 32768);
        ctx_kernel_fb<<<dim3(N_), 256, 0, stream>>>(c, bias, cw, gctx);
        wconv_kernel_fb<<<dim3((COUT * CPG * 9) / 256), 256, 0, stream>>>(wgt, wbf);
        dim3 grid(H_ / FB_TH, GROUPS, N_);
        ctx_conv_fb<<<grid, 512, 0, stream>>>(x, wbf, gctx, out);
    }
}